// Round 1
// baseline (1525.678 us; speedup 1.0000x reference)
//
#include <hip/hip_runtime.h>

#define NN 50000
#define EE 800000
#define ITERS 20
#define KAPPA 0.99f

typedef __bf16 bf16x8 __attribute__((ext_vector_type(8)));
typedef float f32x4 __attribute__((ext_vector_type(4)));
typedef unsigned short u16;
typedef unsigned int u32;

__device__ __forceinline__ u16 f2bf(float f) {
  u32 u = __float_as_uint(f);
  u32 r = u + 0x7FFFu + ((u >> 16) & 1u);
  return (u16)(r >> 16);
}
__device__ __forceinline__ float bflo(u32 x) { return __uint_as_float(x << 16); }
__device__ __forceinline__ float bfhi(u32 x) { return __uint_as_float(x & 0xFFFF0000u); }

// ---------------- W projection (rows onto l1-ball of radius kappa) -> bf16 ----
__global__ __launch_bounds__(128)
void proj_w(const float* __restrict__ W, u16* __restrict__ Wb) {
  __shared__ float su[128];
  __shared__ float scs[128];
  __shared__ int sred[128];
  __shared__ float theta_s, rowsum_s;
  int row = blockIdx.x, t = threadIdx.x;
  float w = W[row * 128 + t];
  float aw = fabsf(w);
  su[t] = aw;
  __syncthreads();
  // bitonic sort ascending
  for (int k = 2; k <= 128; k <<= 1) {
    for (int j = k >> 1; j > 0; j >>= 1) {
      int ixj = t ^ j;
      if (ixj > t) {
        float a = su[t], b = su[ixj];
        if ((t & k) == 0) { if (a > b) { su[t] = b; su[ixj] = a; } }
        else              { if (a < b) { su[t] = b; su[ixj] = a; } }
      }
      __syncthreads();
    }
  }
  float ud = su[127 - t];          // descending view
  scs[t] = ud;
  __syncthreads();
  for (int off = 1; off < 128; off <<= 1) {
    float v = (t >= off) ? scs[t - off] : 0.f;
    __syncthreads();
    scs[t] += v;
    __syncthreads();
  }
  float cs = scs[t] - KAPPA;       // css (inclusive cumsum - kappa)
  sred[t] = ((ud - cs / (float)(t + 1)) > 0.f) ? 1 : 0;
  __syncthreads();
  for (int off = 64; off > 0; off >>= 1) {
    if (t < off) sred[t] += sred[t + off];
    __syncthreads();
  }
  if (t == 0) {
    int rho = sred[0] - 1;          // rho >= 0 always (kappa > 0)
    float th = (scs[rho] - KAPPA) / (float)(rho + 1);
    theta_s = fmaxf(th, 0.f);
    rowsum_s = scs[127];
  }
  __syncthreads();
  float outv;
  if (rowsum_s > KAPPA) {
    float pw = fmaxf(aw - theta_s, 0.f);
    outv = (w >= 0.f) ? pw : -pw;
  } else {
    outv = w;
  }
  Wb[row * 128 + t] = f2bf(outv);
}

// ---------------- small f32 -> bf16 convert ----------------------------------
__global__ __launch_bounds__(256)
void convert_mat(const float* __restrict__ a, u16* __restrict__ o, int count) {
  int i = blockIdx.x * 256 + threadIdx.x;
  if (i < count) o[i] = f2bf(a[i]);
}

// ---------------- U (128 x N) -> Ub (N x 128 bf16) ---------------------------
__global__ __launch_bounds__(256)
void transpose_u(const float* __restrict__ U, u16* __restrict__ Ub, int Nn) {
  __shared__ u16 sh[64][130];
  int n0 = blockIdx.x * 64;
  int t = threadIdx.x;
  int nl = t & 63, pq = t >> 6;
  #pragma unroll
  for (int i = 0; i < 128; i += 4) {
    int p = i + pq;
    int n = n0 + nl;
    float v = (n < Nn) ? U[(size_t)p * Nn + n] : 0.f;
    sh[nl][p] = f2bf(v);
  }
  __syncthreads();
  #pragma unroll
  for (int j = 0; j < 16; ++j) {
    int node = j * 4 + pq;
    int n = n0 + node;
    if (n < Nn) {
      u32 lo = sh[node][nl * 2], hi = sh[node][nl * 2 + 1];
      ((u32*)Ub)[(size_t)n * 64 + nl] = lo | (hi << 16);
    }
  }
}

// ---------------- CSC build --------------------------------------------------
__global__ __launch_bounds__(256)
void hist_k(const int* __restrict__ cols, int* __restrict__ counts) {
  int i = blockIdx.x * 256 + threadIdx.x;
  atomicAdd(&counts[cols[i]], 1);
}

__global__ __launch_bounds__(1024)
void scan_k(const int* __restrict__ counts, int* __restrict__ colptr,
            int* __restrict__ cursor, int Ncols) {
  __shared__ int ssum[1024];
  int t = threadIdx.x;
  const int chunk = (Ncols + 1023) >> 10;
  int b0 = t * chunk;
  int b1 = min(b0 + chunk, Ncols);
  int s = 0;
  for (int i = b0; i < b1; ++i) s += counts[i];
  ssum[t] = s;
  __syncthreads();
  for (int off = 1; off < 1024; off <<= 1) {
    int v = (t >= off) ? ssum[t - off] : 0;
    __syncthreads();
    ssum[t] += v;
    __syncthreads();
  }
  int run = ssum[t] - s;  // exclusive prefix
  for (int i = b0; i < b1; ++i) {
    colptr[i] = run; cursor[i] = run; run += counts[i];
  }
  if (b1 == Ncols) colptr[Ncols] = run;
}

__global__ __launch_bounds__(256)
void scatter_k(const int* __restrict__ rows, const int* __restrict__ cols,
               const float* __restrict__ vals, int* __restrict__ cursor,
               uint2* __restrict__ rv) {
  int i = blockIdx.x * 256 + threadIdx.x;
  int c = cols[i];
  int pos = atomicAdd(&cursor[c], 1);
  rv[pos] = make_uint2((u32)rows[i], __float_as_uint(vals[i]));
}

// ---------------- GEMM: out[n][m] = sum_k Mat[m][k] * Xsrc[n][k] -------------
// Swapped MFMA: A-frag = Mat rows (16B contiguous k), B-frag = node rows.
// D layout (16x16x32): col = lane&15 (node), row = (lane>>4)*4 + reg (m).
template<int OUT_F32>
__global__ __launch_bounds__(256, 2)
void gemm_k(const u16* __restrict__ Mb, const u16* __restrict__ Xsrc,
            void* __restrict__ outp, int ntiles) {
  int lane = threadIdx.x & 63;
  int wid = threadIdx.x >> 6;
  int r = lane & 15, kg = lane >> 4;
  bf16x8 wf[8][4];
  #pragma unroll
  for (int mt = 0; mt < 8; ++mt)
    #pragma unroll
    for (int kk = 0; kk < 4; ++kk)
      wf[mt][kk] = *reinterpret_cast<const bf16x8*>(
          Mb + (mt * 16 + r) * 128 + kk * 32 + kg * 8);
  int nw = gridDim.x * 4;
  for (int t = blockIdx.x * 4 + wid; t < ntiles; t += nw) {
    const u16* xp = Xsrc + (size_t)(t * 16 + r) * 128 + kg * 8;
    bf16x8 xf[4];
    #pragma unroll
    for (int kk = 0; kk < 4; ++kk)
      xf[kk] = *reinterpret_cast<const bf16x8*>(xp + kk * 32);
    f32x4 acc[8];
    #pragma unroll
    for (int mt = 0; mt < 8; ++mt) acc[mt] = (f32x4)(0.f);
    #pragma unroll
    for (int mt = 0; mt < 8; ++mt)
      #pragma unroll
      for (int kk = 0; kk < 4; ++kk)
        acc[mt] = __builtin_amdgcn_mfma_f32_16x16x32_bf16(
            wf[mt][kk], xf[kk], acc[mt], 0, 0, 0);
    if (OUT_F32) {
      float* o = (float*)outp + (size_t)(t * 16 + r) * 128 + kg * 4;
      #pragma unroll
      for (int mt = 0; mt < 8; ++mt)
        *reinterpret_cast<f32x4*>(o + mt * 16) = acc[mt];
    } else {
      u16* o = (u16*)outp + (size_t)(t * 16 + r) * 128 + kg * 4;
      #pragma unroll
      for (int mt = 0; mt < 8; ++mt) {
        uint2 pk;
        pk.x = (u32)f2bf(acc[mt][0]) | ((u32)f2bf(acc[mt][1]) << 16);
        pk.y = (u32)f2bf(acc[mt][2]) | ((u32)f2bf(acc[mt][3]) << 16);
        *reinterpret_cast<uint2*>(o + mt * 16) = pk;
      }
    }
  }
}

// ---------------- SpMM gather: one wave per output node ----------------------
// MODE 0: bias build  (Bf += gather, no relu, write Bf + Xb)
// MODE 1: iteration   (relu(gather + Bf) -> Xb)
// MODE 2: last iter   (also write fp32 Xf)
template<int MODE>
__global__ __launch_bounds__(256, 4)
void spmm_k(const int* __restrict__ colptr, const uint2* __restrict__ rv,
            const u16* __restrict__ Src, float* __restrict__ Bf,
            u16* __restrict__ Xb, float* __restrict__ Xf) {
  int n = (blockIdx.x << 2) + (threadIdx.x >> 6);
  int lane = threadIdx.x & 63;
  int beg = colptr[n];
  int end = colptr[n + 1];
  float a0 = 0.f, a1 = 0.f;
  int e = beg;
  for (; e + 4 <= end; e += 4) {
    uint2 p0 = rv[e], p1 = rv[e + 1], p2 = rv[e + 2], p3 = rv[e + 3];
    u32 x0 = *(const u32*)(Src + (size_t)p0.x * 128 + (lane << 1));
    u32 x1 = *(const u32*)(Src + (size_t)p1.x * 128 + (lane << 1));
    u32 x2 = *(const u32*)(Src + (size_t)p2.x * 128 + (lane << 1));
    u32 x3 = *(const u32*)(Src + (size_t)p3.x * 128 + (lane << 1));
    float v0 = __uint_as_float(p0.y), v1 = __uint_as_float(p1.y);
    float v2 = __uint_as_float(p2.y), v3 = __uint_as_float(p3.y);
    a0 += v0 * bflo(x0); a1 += v0 * bfhi(x0);
    a0 += v1 * bflo(x1); a1 += v1 * bfhi(x1);
    a0 += v2 * bflo(x2); a1 += v2 * bfhi(x2);
    a0 += v3 * bflo(x3); a1 += v3 * bfhi(x3);
  }
  for (; e < end; ++e) {
    uint2 p = rv[e];
    u32 x = *(const u32*)(Src + (size_t)p.x * 128 + (lane << 1));
    float v = __uint_as_float(p.y);
    a0 += v * bflo(x); a1 += v * bfhi(x);
  }
  float2 b = *(const float2*)(Bf + (size_t)n * 128 + (lane << 1));
  float o0 = a0 + b.x, o1 = a1 + b.y;
  if (MODE >= 1) { o0 = fmaxf(o0, 0.f); o1 = fmaxf(o1, 0.f); }
  if (MODE == 0)
    *(float2*)(Bf + (size_t)n * 128 + (lane << 1)) = make_float2(o0, o1);
  *(u32*)(Xb + (size_t)n * 128 + (lane << 1)) =
      (u32)f2bf(o0) | ((u32)f2bf(o1) << 16);
  if (MODE == 2)
    *(float2*)(Xf + (size_t)n * 128 + (lane << 1)) = make_float2(o0, o1);
}

// ---------------- Xf (N x 128 f32) -> out (128 x N f32) ----------------------
__global__ __launch_bounds__(256)
void transpose_out(const float* __restrict__ Xf, float* __restrict__ out, int Nn) {
  __shared__ float sh[128][65];
  int n0 = blockIdx.x * 64;
  int t = threadIdx.x;
  #pragma unroll
  for (int i = 0; i < 32; ++i) {
    int idx = i * 256 + t;
    int node = idx >> 7, m = idx & 127;
    int n = n0 + node;
    float v = (n < Nn) ? Xf[(size_t)n * 128 + m] : 0.f;
    sh[m][node] = v;
  }
  __syncthreads();
  #pragma unroll
  for (int i = 0; i < 32; ++i) {
    int idx = i * 256 + t;
    int m = idx >> 6, nl = idx & 63;
    int n = n0 + nl;
    if (n < Nn) out[(size_t)m * Nn + n] = sh[m][nl];
  }
}

// ---------------- launcher ---------------------------------------------------
extern "C" void kernel_launch(void* const* d_in, const int* in_sizes, int n_in,
                              void* d_out, int out_size, void* d_ws, size_t ws_size,
                              hipStream_t stream) {
  (void)in_sizes; (void)n_in; (void)out_size; (void)ws_size;
  const float* U   = (const float*)d_in[0];
  const int*   er  = (const int*)d_in[1];
  const int*   ec  = (const int*)d_in[2];
  const float* ev  = (const float*)d_in[3];
  const float* W   = (const float*)d_in[4];
  const float* Om1 = (const float*)d_in[5];
  const float* Om2 = (const float*)d_in[6];
  float* out = (float*)d_out;

  char* base = (char*)d_ws;
  size_t off = 0;
  auto alloc = [&](size_t b) {
    char* p = base + off;
    off = (off + b + 255) & ~(size_t)255;
    return p;
  };
  u16* Wb    = (u16*)alloc(128 * 128 * 2);
  u16* Om1b  = (u16*)alloc(128 * 128 * 2);
  u16* Om2b  = (u16*)alloc(128 * 128 * 2);
  float* Xf  = (float*)alloc((size_t)NN * 128 * 4);  // aliased: Ub lives here too
  u16* Ub    = (u16*)Xf;                             // Ub dead before Xf written
  u16* Xb    = (u16*)alloc((size_t)NN * 128 * 2);
  u16* Xwb   = (u16*)alloc((size_t)NN * 128 * 2);
  float* Bf  = (float*)alloc((size_t)NN * 128 * 4);
  int* counts = (int*)alloc((size_t)NN * 4);
  int* colptr = (int*)alloc((size_t)(NN + 1) * 4);
  int* cursor = (int*)alloc((size_t)NN * 4);
  uint2* rv   = (uint2*)alloc((size_t)EE * 8);

  // setup: projection, converts, transpose, CSC build
  proj_w<<<dim3(128), dim3(128), 0, stream>>>(W, Wb);
  convert_mat<<<dim3(64), dim3(256), 0, stream>>>(Om1, Om1b, 128 * 128);
  convert_mat<<<dim3(64), dim3(256), 0, stream>>>(Om2, Om2b, 128 * 128);
  transpose_u<<<dim3((NN + 63) / 64), dim3(256), 0, stream>>>(U, Ub, NN);
  hipMemsetAsync(counts, 0, (size_t)NN * 4, stream);
  hist_k<<<dim3(EE / 256), dim3(256), 0, stream>>>(ec, counts);
  scan_k<<<dim3(1), dim3(1024), 0, stream>>>(counts, colptr, cursor, NN);
  scatter_k<<<dim3(EE / 256), dim3(256), 0, stream>>>(er, ec, ev, cursor, rv);

  // B = scatter(Omega_1 @ U) + Omega_2 @ U ;  X_0 = B
  gemm_k<0><<<dim3(512), dim3(256), 0, stream>>>(Om1b, Ub, (void*)Xwb, NN / 16);
  gemm_k<1><<<dim3(512), dim3(256), 0, stream>>>(Om2b, Ub, (void*)Bf, NN / 16);
  spmm_k<0><<<dim3(NN / 4), dim3(256), 0, stream>>>(colptr, rv, Xwb, Bf, Xb, (float*)nullptr);

  // 20 fixed-point iterations
  for (int it = 0; it < ITERS; ++it) {
    gemm_k<0><<<dim3(512), dim3(256), 0, stream>>>(Wb, Xb, (void*)Xwb, NN / 16);
    if (it < ITERS - 1)
      spmm_k<1><<<dim3(NN / 4), dim3(256), 0, stream>>>(colptr, rv, Xwb, Bf, Xb, (float*)nullptr);
    else
      spmm_k<2><<<dim3(NN / 4), dim3(256), 0, stream>>>(colptr, rv, Xwb, Bf, Xb, Xf);
  }

  transpose_out<<<dim3((NN + 63) / 64), dim3(256), 0, stream>>>(Xf, out, NN);
}

// Round 4
// 1285.312 us; speedup vs baseline: 1.1870x; 1.1870x over previous
//
#include <hip/hip_runtime.h>

#define NN 50000
#define EE 800000
#define ITERS 20
#define KAPPA 0.99f
#define NTILES 3125   // NN/16
#define NB1 196       // ceil(NN/256)

typedef __bf16 bf16x8 __attribute__((ext_vector_type(8)));
typedef float f32x4 __attribute__((ext_vector_type(4)));
typedef unsigned short u16;
typedef unsigned int u32;

__device__ __forceinline__ u16 f2bf(float f) {
  u32 u = __float_as_uint(f);
  u32 r = u + 0x7FFFu + ((u >> 16) & 1u);
  return (u16)(r >> 16);
}
__device__ __forceinline__ u32 pack2bf(float a, float b) {
  return (u32)f2bf(a) | ((u32)f2bf(b) << 16);
}
__device__ __forceinline__ float bflo(u32 x) { return __uint_as_float(x << 16); }
__device__ __forceinline__ float bfhi(u32 x) { return __uint_as_float(x & 0xFFFF0000u); }

// ---------------- W projection (rows onto l1-ball of radius kappa) -> bf16 ----
__global__ __launch_bounds__(128)
void proj_w(const float* __restrict__ W, u16* __restrict__ Wb) {
  __shared__ float su[128];
  __shared__ float scs[128];
  __shared__ int sred[128];
  __shared__ float theta_s, rowsum_s;
  int row = blockIdx.x, t = threadIdx.x;
  float w = W[row * 128 + t];
  float aw = fabsf(w);
  su[t] = aw;
  __syncthreads();
  for (int k = 2; k <= 128; k <<= 1) {
    for (int j = k >> 1; j > 0; j >>= 1) {
      int ixj = t ^ j;
      if (ixj > t) {
        float a = su[t], b = su[ixj];
        if ((t & k) == 0) { if (a > b) { su[t] = b; su[ixj] = a; } }
        else              { if (a < b) { su[t] = b; su[ixj] = a; } }
      }
      __syncthreads();
    }
  }
  float ud = su[127 - t];
  scs[t] = ud;
  __syncthreads();
  for (int off = 1; off < 128; off <<= 1) {
    float v = (t >= off) ? scs[t - off] : 0.f;
    __syncthreads();
    scs[t] += v;
    __syncthreads();
  }
  float cs = scs[t] - KAPPA;
  sred[t] = ((ud - cs / (float)(t + 1)) > 0.f) ? 1 : 0;
  __syncthreads();
  for (int off = 64; off > 0; off >>= 1) {
    if (t < off) sred[t] += sred[t + off];
    __syncthreads();
  }
  if (t == 0) {
    int rho = sred[0] - 1;
    float th = (scs[rho] - KAPPA) / (float)(rho + 1);
    theta_s = fmaxf(th, 0.f);
    rowsum_s = scs[127];
  }
  __syncthreads();
  float outv;
  if (rowsum_s > KAPPA) {
    float pw = fmaxf(aw - theta_s, 0.f);
    outv = (w >= 0.f) ? pw : -pw;
  } else {
    outv = w;
  }
  Wb[row * 128 + t] = f2bf(outv);
}

// ---------------- small f32 -> bf16 convert ----------------------------------
__global__ __launch_bounds__(256)
void convert_mat(const float* __restrict__ a, u16* __restrict__ o, int count) {
  int i = blockIdx.x * 256 + threadIdx.x;
  if (i < count) o[i] = f2bf(a[i]);
}

// ---------------- U (128 x N) -> Ub (N x 128 bf16) ---------------------------
__global__ __launch_bounds__(256)
void transpose_u(const float* __restrict__ U, u16* __restrict__ Ub, int Nn) {
  __shared__ u16 sh[64][130];
  int n0 = blockIdx.x * 64;
  int t = threadIdx.x;
  int nl = t & 63, pq = t >> 6;
  #pragma unroll
  for (int i = 0; i < 128; i += 4) {
    int p = i + pq;
    int n = n0 + nl;
    float v = (n < Nn) ? U[(size_t)p * Nn + n] : 0.f;
    sh[nl][p] = f2bf(v);
  }
  __syncthreads();
  #pragma unroll
  for (int j = 0; j < 16; ++j) {
    int node = j * 4 + pq;
    int n = n0 + node;
    if (n < Nn) {
      u32 lo = sh[node][nl * 2], hi = sh[node][nl * 2 + 1];
      ((u32*)Ub)[(size_t)n * 64 + nl] = lo | (hi << 16);
    }
  }
}

// ---------------- CSC build --------------------------------------------------
__global__ __launch_bounds__(256)
void hist_k(const int* __restrict__ cols, int* __restrict__ counts) {
  int i = blockIdx.x * 256 + threadIdx.x;
  atomicAdd(&counts[cols[i]], 1);
}

// decoupled 3-kernel scan (all coalesced)
__global__ __launch_bounds__(256)
void scan1(const int* __restrict__ counts, int* __restrict__ bsums) {
  __shared__ int s[256];
  int t = threadIdx.x;
  int i = blockIdx.x * 256 + t;
  s[t] = (i < NN) ? counts[i] : 0;
  __syncthreads();
  for (int off = 128; off > 0; off >>= 1) {
    if (t < off) s[t] += s[t + off];
    __syncthreads();
  }
  if (t == 0) bsums[blockIdx.x] = s[0];
}

__global__ __launch_bounds__(256)
void scan2(const int* __restrict__ bsums, int* __restrict__ boffs) {
  __shared__ int s[256];
  int t = threadIdx.x;
  int v = (t < NB1) ? bsums[t] : 0;
  s[t] = v;
  __syncthreads();
  for (int off = 1; off < 256; off <<= 1) {
    int u = (t >= off) ? s[t - off] : 0;
    __syncthreads();
    s[t] += u;
    __syncthreads();
  }
  if (t < NB1) boffs[t] = s[t] - v;   // exclusive
}

__global__ __launch_bounds__(256)
void scan3(const int* __restrict__ counts, const int* __restrict__ boffs,
           int* __restrict__ colptr, int* __restrict__ cursor) {
  __shared__ int s[256];
  int t = threadIdx.x;
  int i = blockIdx.x * 256 + t;
  int v = (i < NN) ? counts[i] : 0;
  s[t] = v;
  __syncthreads();
  for (int off = 1; off < 256; off <<= 1) {
    int u = (t >= off) ? s[t - off] : 0;
    __syncthreads();
    s[t] += u;
    __syncthreads();
  }
  int excl = s[t] - v + boffs[blockIdx.x];
  if (i < NN) { colptr[i] = excl; cursor[i] = excl; }
  if (i == 0) colptr[NN] = EE;
}

__global__ __launch_bounds__(256)
void scatter_k(const int* __restrict__ rows, const int* __restrict__ cols,
               const float* __restrict__ vals, int* __restrict__ cursor,
               uint2* __restrict__ rv) {
  int i = blockIdx.x * 256 + threadIdx.x;
  int c = cols[i];
  int pos = atomicAdd(&cursor[c], 1);
  rv[pos] = make_uint2((u32)rows[i], __float_as_uint(vals[i]));
}

// ---------------- GEMM: out[n][m] = sum_k Mat[m][k] * Xsrc[n][k] -------------
// Swapped MFMA; 1-deep software prefetch of the next X tile across the
// grid-stride loop. Output packed bf16 (u32 pairs).
__global__ __launch_bounds__(256, 2)
void gemm_k(const u16* __restrict__ Mb, const u16* __restrict__ Xsrc,
            u32* __restrict__ outp) {
  int lane = threadIdx.x & 63;
  int wid = threadIdx.x >> 6;
  int r = lane & 15, kg = lane >> 4;
  bf16x8 wf[8][4];
  #pragma unroll
  for (int mt = 0; mt < 8; ++mt)
    #pragma unroll
    for (int kk = 0; kk < 4; ++kk)
      wf[mt][kk] = *reinterpret_cast<const bf16x8*>(
          Mb + (mt * 16 + r) * 128 + kk * 32 + kg * 8);
  const int nw = gridDim.x * 4;
  int t = blockIdx.x * 4 + wid;
  if (t >= NTILES) return;
  bf16x8 xc[4], xn[4];
  {
    const u16* xp = Xsrc + (size_t)(t * 16 + r) * 128 + kg * 8;
    #pragma unroll
    for (int kk = 0; kk < 4; ++kk)
      xc[kk] = *reinterpret_cast<const bf16x8*>(xp + kk * 32);
  }
  while (true) {
    int nxt = t + nw;
    bool has = (nxt < NTILES);
    if (has) {
      const u16* xp = Xsrc + (size_t)(nxt * 16 + r) * 128 + kg * 8;
      #pragma unroll
      for (int kk = 0; kk < 4; ++kk)
        xn[kk] = *reinterpret_cast<const bf16x8*>(xp + kk * 32);
    }
    f32x4 acc[8];
    #pragma unroll
    for (int mt = 0; mt < 8; ++mt) acc[mt] = (f32x4)(0.f);
    #pragma unroll
    for (int mt = 0; mt < 8; ++mt)
      #pragma unroll
      for (int kk = 0; kk < 4; ++kk)
        acc[mt] = __builtin_amdgcn_mfma_f32_16x16x32_bf16(
            wf[mt][kk], xc[kk], acc[mt], 0, 0, 0);
    u32* o = outp + (size_t)(t * 16 + r) * 64 + kg * 2;
    #pragma unroll
    for (int mt = 0; mt < 8; ++mt) {
      uint2 pk;
      pk.x = pack2bf(acc[mt][0], acc[mt][1]);
      pk.y = pack2bf(acc[mt][2], acc[mt][3]);
      *reinterpret_cast<uint2*>(o + mt * 8) = pk;
    }
    if (!has) break;
    #pragma unroll
    for (int kk = 0; kk < 4; ++kk) xc[kk] = xn[kk];
    t = nxt;
  }
}

// ---------------- SpMM gather: one wave per output node ----------------------
// Coalesced rv load (edge e -> lane e), rows/vals broadcast via __shfl so all
// 8 gather loads per round are issued back-to-back (one latency, 8 in flight).
// MODE 0: bias build  Bb += gather (no relu), write Bb packed bf16
// MODE 1: iteration   relu(gather + Bb) -> Xb packed bf16
// MODE 2: last iter   relu(gather + Bb) -> Xf fp32
template<int MODE>
__global__ __launch_bounds__(256, 8)
void spmm_k(const int* __restrict__ colptr, const uint2* __restrict__ rv,
            const u16* __restrict__ Src, u32* __restrict__ Bb,
            u32* __restrict__ Xb, float* __restrict__ Xf) {
  int n = (blockIdx.x << 2) + (threadIdx.x >> 6);
  int lane = threadIdx.x & 63;
  int beg = colptr[n];
  int end = colptr[n + 1];
  int deg = end - beg;
  const u16* sp = Src + (lane << 1);
  float a0 = 0.f, a1 = 0.f, c0 = 0.f, c1 = 0.f;
  if (deg > 0) {
    if (deg <= 64) {
      uint2 p = rv[beg + ((lane < deg) ? lane : 0)];
      int rr = (int)p.x;
      float vv = __uint_as_float(p.y);
      int e = 0;
      for (; e + 8 <= deg; e += 8) {
        int ri[8]; u32 xi[8]; float vi[8];
        #pragma unroll
        for (int j = 0; j < 8; ++j) ri[j] = __shfl(rr, e + j);
        #pragma unroll
        for (int j = 0; j < 8; ++j) xi[j] = *(const u32*)(sp + ri[j] * 128);
        #pragma unroll
        for (int j = 0; j < 8; ++j) vi[j] = __shfl(vv, e + j);
        #pragma unroll
        for (int j = 0; j < 8; ++j) {
          if (j & 1) { c0 += vi[j] * bflo(xi[j]); c1 += vi[j] * bfhi(xi[j]); }
          else       { a0 += vi[j] * bflo(xi[j]); a1 += vi[j] * bfhi(xi[j]); }
        }
      }
      for (; e < deg; ++e) {
        int re = __shfl(rr, e);
        float ve = __shfl(vv, e);
        u32 x = *(const u32*)(sp + re * 128);
        a0 += ve * bflo(x); a1 += ve * bfhi(x);
      }
    } else {
      for (int e = beg; e < end; ++e) {
        uint2 p = rv[e];
        u32 x = *(const u32*)(sp + (int)p.x * 128);
        float v = __uint_as_float(p.y);
        a0 += v * bflo(x); a1 += v * bfhi(x);
      }
    }
  }
  a0 += c0; a1 += c1;
  u32 bp = Bb[(size_t)n * 64 + lane];
  float o0 = a0 + bflo(bp), o1 = a1 + bfhi(bp);
  if (MODE >= 1) { o0 = fmaxf(o0, 0.f); o1 = fmaxf(o1, 0.f); }
  if (MODE == 0) Bb[(size_t)n * 64 + lane] = pack2bf(o0, o1);
  if (MODE == 1) Xb[(size_t)n * 64 + lane] = pack2bf(o0, o1);
  if (MODE == 2)
    *(float2*)(Xf + (size_t)n * 128 + (lane << 1)) = make_float2(o0, o1);
}

// ---------------- Xf (N x 128 f32) -> out (128 x N f32) ----------------------
__global__ __launch_bounds__(256)
void transpose_out(const float* __restrict__ Xf, float* __restrict__ out, int Nn) {
  __shared__ float sh[128][65];
  int n0 = blockIdx.x * 64;
  int t = threadIdx.x;
  #pragma unroll
  for (int i = 0; i < 32; ++i) {
    int idx = i * 256 + t;
    int node = idx >> 7, m = idx & 127;
    int n = n0 + node;
    float v = (n < Nn) ? Xf[(size_t)n * 128 + m] : 0.f;
    sh[m][node] = v;
  }
  __syncthreads();
  #pragma unroll
  for (int i = 0; i < 32; ++i) {
    int idx = i * 256 + t;
    int m = idx >> 6, nl = idx & 63;
    int n = n0 + nl;
    if (n < Nn) out[(size_t)m * Nn + n] = sh[m][nl];
  }
}

// ---------------- launcher ---------------------------------------------------
extern "C" void kernel_launch(void* const* d_in, const int* in_sizes, int n_in,
                              void* d_out, int out_size, void* d_ws, size_t ws_size,
                              hipStream_t stream) {
  (void)in_sizes; (void)n_in; (void)out_size; (void)ws_size;
  const float* U   = (const float*)d_in[0];
  const int*   er  = (const int*)d_in[1];
  const int*   ec  = (const int*)d_in[2];
  const float* ev  = (const float*)d_in[3];
  const float* W   = (const float*)d_in[4];
  const float* Om1 = (const float*)d_in[5];
  const float* Om2 = (const float*)d_in[6];
  float* out = (float*)d_out;

  char* base = (char*)d_ws;
  size_t off = 0;
  auto alloc = [&](size_t b) {
    char* p = base + off;
    off = (off + b + 255) & ~(size_t)255;
    return p;
  };
  u16* Wb     = (u16*)alloc(128 * 128 * 2);
  u16* Om1b   = (u16*)alloc(128 * 128 * 2);
  u16* Om2b   = (u16*)alloc(128 * 128 * 2);
  float* Xf   = (float*)alloc((size_t)NN * 128 * 4);  // aliased: Ub lives here
  u16* Ub     = (u16*)Xf;                             // Ub dead before Xf written
  u32* Xb     = (u32*)alloc((size_t)NN * 64 * 4);
  u32* Xwb    = (u32*)alloc((size_t)NN * 64 * 4);
  u32* Bb     = (u32*)alloc((size_t)NN * 64 * 4);
  int* counts = (int*)alloc((size_t)NN * 4);
  int* colptr = (int*)alloc((size_t)(NN + 1) * 4);
  int* cursor = (int*)alloc((size_t)NN * 4);
  int* bsums  = (int*)alloc((size_t)NB1 * 4);
  int* boffs  = (int*)alloc((size_t)NB1 * 4);
  uint2* rv   = (uint2*)alloc((size_t)EE * 8);

  // setup: projection, converts, transpose, CSC build
  proj_w<<<dim3(128), dim3(128), 0, stream>>>(W, Wb);
  convert_mat<<<dim3(64), dim3(256), 0, stream>>>(Om1, Om1b, 128 * 128);
  convert_mat<<<dim3(64), dim3(256), 0, stream>>>(Om2, Om2b, 128 * 128);
  transpose_u<<<dim3((NN + 63) / 64), dim3(256), 0, stream>>>(U, Ub, NN);
  hipMemsetAsync(counts, 0, (size_t)NN * 4, stream);
  hist_k<<<dim3(EE / 256), dim3(256), 0, stream>>>(ec, counts);
  scan1<<<dim3(NB1), dim3(256), 0, stream>>>(counts, bsums);
  scan2<<<dim3(1), dim3(256), 0, stream>>>(bsums, boffs);
  scan3<<<dim3(NB1), dim3(256), 0, stream>>>(counts, boffs, colptr, cursor);
  scatter_k<<<dim3(EE / 256), dim3(256), 0, stream>>>(er, ec, ev, cursor, rv);

  // B = gather(Omega_1 @ U) + Omega_2 @ U  (Bb holds bf16 B); X_0 = B
  gemm_k<<<dim3(512), dim3(256), 0, stream>>>(Om1b, Ub, Xwb);
  gemm_k<<<dim3(512), dim3(256), 0, stream>>>(Om2b, Ub, Bb);
  spmm_k<0><<<dim3(NN / 4), dim3(256), 0, stream>>>(colptr, rv, (const u16*)Xwb,
                                                    Bb, (u32*)nullptr, (float*)nullptr);

  // 20 fixed-point iterations (X_0 = B lives in Bb for the first gemm)
  for (int it = 0; it < ITERS; ++it) {
    const u16* xsrc = (it == 0) ? (const u16*)Bb : (const u16*)Xb;
    gemm_k<<<dim3(512), dim3(256), 0, stream>>>(Wb, xsrc, Xwb);
    if (it < ITERS - 1)
      spmm_k<1><<<dim3(NN / 4), dim3(256), 0, stream>>>(colptr, rv, (const u16*)Xwb,
                                                        Bb, Xb, (float*)nullptr);
    else
      spmm_k<2><<<dim3(NN / 4), dim3(256), 0, stream>>>(colptr, rv, (const u16*)Xwb,
                                                        Bb, (u32*)nullptr, Xf);
  }

  transpose_out<<<dim3((NN + 63) / 64), dim3(256), 0, stream>>>(Xf, out, NN);
}

// Round 5
// 1221.226 us; speedup vs baseline: 1.2493x; 1.0525x over previous
//
#include <hip/hip_runtime.h>

#define NN 50000
#define EE 800000
#define ITERS 20
#define KAPPA 0.99f
#define NTILES 3125   // NN/16
#define NB1 196       // ceil(NN/256)
#define SC_PASSES 8
#define SC_BLOCKS (EE / 256)   // 3125
#define SC_RANGE (NN / SC_PASSES) // 6250

typedef __bf16 bf16x8 __attribute__((ext_vector_type(8)));
typedef float f32x4 __attribute__((ext_vector_type(4)));
typedef unsigned short u16;
typedef unsigned int u32;

__device__ __forceinline__ u16 f2bf(float f) {
  u32 u = __float_as_uint(f);
  u32 r = u + 0x7FFFu + ((u >> 16) & 1u);
  return (u16)(r >> 16);
}
__device__ __forceinline__ u32 pack2bf(float a, float b) {
  return (u32)f2bf(a) | ((u32)f2bf(b) << 16);
}
__device__ __forceinline__ float bflo(u32 x) { return __uint_as_float(x << 16); }
__device__ __forceinline__ float bfhi(u32 x) { return __uint_as_float(x & 0xFFFF0000u); }

// ---------------- W projection (rows onto l1-ball of radius kappa) -> bf16 ----
__global__ __launch_bounds__(128)
void proj_w(const float* __restrict__ W, u16* __restrict__ Wb) {
  __shared__ float su[128];
  __shared__ float scs[128];
  __shared__ int sred[128];
  __shared__ float theta_s, rowsum_s;
  int row = blockIdx.x, t = threadIdx.x;
  float w = W[row * 128 + t];
  float aw = fabsf(w);
  su[t] = aw;
  __syncthreads();
  for (int k = 2; k <= 128; k <<= 1) {
    for (int j = k >> 1; j > 0; j >>= 1) {
      int ixj = t ^ j;
      if (ixj > t) {
        float a = su[t], b = su[ixj];
        if ((t & k) == 0) { if (a > b) { su[t] = b; su[ixj] = a; } }
        else              { if (a < b) { su[t] = b; su[ixj] = a; } }
      }
      __syncthreads();
    }
  }
  float ud = su[127 - t];
  scs[t] = ud;
  __syncthreads();
  for (int off = 1; off < 128; off <<= 1) {
    float v = (t >= off) ? scs[t - off] : 0.f;
    __syncthreads();
    scs[t] += v;
    __syncthreads();
  }
  float cs = scs[t] - KAPPA;
  sred[t] = ((ud - cs / (float)(t + 1)) > 0.f) ? 1 : 0;
  __syncthreads();
  for (int off = 64; off > 0; off >>= 1) {
    if (t < off) sred[t] += sred[t + off];
    __syncthreads();
  }
  if (t == 0) {
    int rho = sred[0] - 1;
    float th = (scs[rho] - KAPPA) / (float)(rho + 1);
    theta_s = fmaxf(th, 0.f);
    rowsum_s = scs[127];
  }
  __syncthreads();
  float outv;
  if (rowsum_s > KAPPA) {
    float pw = fmaxf(aw - theta_s, 0.f);
    outv = (w >= 0.f) ? pw : -pw;
  } else {
    outv = w;
  }
  Wb[row * 128 + t] = f2bf(outv);
}

// ---------------- two small f32 -> bf16 converts fused -----------------------
__global__ __launch_bounds__(256)
void convert_mat2(const float* __restrict__ a, const float* __restrict__ b,
                  u16* __restrict__ oa, u16* __restrict__ ob) {
  int i = blockIdx.x * 256 + threadIdx.x;
  if (i < 16384) oa[i] = f2bf(a[i]);
  else           ob[i - 16384] = f2bf(b[i - 16384]);
}

// ---------------- U (128 x N) -> Ub (N x 128 bf16) ---------------------------
__global__ __launch_bounds__(256)
void transpose_u(const float* __restrict__ U, u16* __restrict__ Ub, int Nn) {
  __shared__ u16 sh[64][130];
  int n0 = blockIdx.x * 64;
  int t = threadIdx.x;
  int nl = t & 63, pq = t >> 6;
  #pragma unroll
  for (int i = 0; i < 128; i += 4) {
    int p = i + pq;
    int n = n0 + nl;
    float v = (n < Nn) ? U[(size_t)p * Nn + n] : 0.f;
    sh[nl][p] = f2bf(v);
  }
  __syncthreads();
  #pragma unroll
  for (int j = 0; j < 16; ++j) {
    int node = j * 4 + pq;
    int n = n0 + node;
    if (n < Nn) {
      u32 lo = sh[node][nl * 2], hi = sh[node][nl * 2 + 1];
      ((u32*)Ub)[(size_t)n * 64 + nl] = lo | (hi << 16);
    }
  }
}

// ---------------- CSC build --------------------------------------------------
__global__ __launch_bounds__(256)
void hist_k(const int* __restrict__ cols, int* __restrict__ counts) {
  int i = blockIdx.x * 256 + threadIdx.x;
  atomicAdd(&counts[cols[i]], 1);
}

// decoupled 3-kernel scan (all coalesced)
__global__ __launch_bounds__(256)
void scan1(const int* __restrict__ counts, int* __restrict__ bsums) {
  __shared__ int s[256];
  int t = threadIdx.x;
  int i = blockIdx.x * 256 + t;
  s[t] = (i < NN) ? counts[i] : 0;
  __syncthreads();
  for (int off = 128; off > 0; off >>= 1) {
    if (t < off) s[t] += s[t + off];
    __syncthreads();
  }
  if (t == 0) bsums[blockIdx.x] = s[0];
}

__global__ __launch_bounds__(256)
void scan2(const int* __restrict__ bsums, int* __restrict__ boffs) {
  __shared__ int s[256];
  int t = threadIdx.x;
  int v = (t < NB1) ? bsums[t] : 0;
  s[t] = v;
  __syncthreads();
  for (int off = 1; off < 256; off <<= 1) {
    int u = (t >= off) ? s[t - off] : 0;
    __syncthreads();
    s[t] += u;
    __syncthreads();
  }
  if (t < NB1) boffs[t] = s[t] - v;   // exclusive
}

__global__ __launch_bounds__(256)
void scan3(const int* __restrict__ counts, const int* __restrict__ boffs,
           int* __restrict__ colptr, int* __restrict__ cursor) {
  __shared__ int s[256];
  int t = threadIdx.x;
  int i = blockIdx.x * 256 + t;
  int v = (i < NN) ? counts[i] : 0;
  s[t] = v;
  __syncthreads();
  for (int off = 1; off < 256; off <<= 1) {
    int u = (t >= off) ? s[t - off] : 0;
    __syncthreads();
    s[t] += u;
    __syncthreads();
  }
  int excl = s[t] - v + boffs[blockIdx.x];
  if (i < NN) { colptr[i] = excl; cursor[i] = excl; }
  if (i == 0) colptr[NN] = EE;
}

// 8 column-range passes: each pass's writes land in a ~0.8 MB L2-resident
// window, killing the 8x line-writeback amplification of a full random scatter.
// pass = blockIdx.x / SC_BLOCKS, so dispatch order clusters passes in time.
__global__ __launch_bounds__(256)
void scatter_k(const int* __restrict__ rows, const int* __restrict__ cols,
               const float* __restrict__ vals, int* __restrict__ cursor,
               uint2* __restrict__ rv) {
  int pass = blockIdx.x / SC_BLOCKS;
  int i = (blockIdx.x % SC_BLOCKS) * 256 + threadIdx.x;
  int c = cols[i];
  int lo = pass * SC_RANGE;
  if (c >= lo && c < lo + SC_RANGE) {
    int pos = atomicAdd(&cursor[c], 1);
    rv[pos] = make_uint2((u32)rows[i], __float_as_uint(vals[i]));
  }
}

// ---------------- GEMM: out[n][m] = sum_k Mat[m][k] * Xsrc[n][k] -------------
// Swapped MFMA; 1-deep software prefetch of the next X tile across the
// grid-stride loop. Output packed bf16 (u32 pairs).
__global__ __launch_bounds__(256, 2)
void gemm_k(const u16* __restrict__ Mb, const u16* __restrict__ Xsrc,
            u32* __restrict__ outp) {
  int lane = threadIdx.x & 63;
  int wid = threadIdx.x >> 6;
  int r = lane & 15, kg = lane >> 4;
  bf16x8 wf[8][4];
  #pragma unroll
  for (int mt = 0; mt < 8; ++mt)
    #pragma unroll
    for (int kk = 0; kk < 4; ++kk)
      wf[mt][kk] = *reinterpret_cast<const bf16x8*>(
          Mb + (mt * 16 + r) * 128 + kk * 32 + kg * 8);
  const int nw = gridDim.x * 4;
  int t = blockIdx.x * 4 + wid;
  if (t >= NTILES) return;
  bf16x8 xc[4], xn[4];
  {
    const u16* xp = Xsrc + (size_t)(t * 16 + r) * 128 + kg * 8;
    #pragma unroll
    for (int kk = 0; kk < 4; ++kk)
      xc[kk] = *reinterpret_cast<const bf16x8*>(xp + kk * 32);
  }
  while (true) {
    int nxt = t + nw;
    bool has = (nxt < NTILES);
    if (has) {
      const u16* xp = Xsrc + (size_t)(nxt * 16 + r) * 128 + kg * 8;
      #pragma unroll
      for (int kk = 0; kk < 4; ++kk)
        xn[kk] = *reinterpret_cast<const bf16x8*>(xp + kk * 32);
    }
    f32x4 acc[8];
    #pragma unroll
    for (int mt = 0; mt < 8; ++mt) acc[mt] = (f32x4)(0.f);
    #pragma unroll
    for (int mt = 0; mt < 8; ++mt)
      #pragma unroll
      for (int kk = 0; kk < 4; ++kk)
        acc[mt] = __builtin_amdgcn_mfma_f32_16x16x32_bf16(
            wf[mt][kk], xc[kk], acc[mt], 0, 0, 0);
    u32* o = outp + (size_t)(t * 16 + r) * 64 + kg * 2;
    #pragma unroll
    for (int mt = 0; mt < 8; ++mt) {
      uint2 pk;
      pk.x = pack2bf(acc[mt][0], acc[mt][1]);
      pk.y = pack2bf(acc[mt][2], acc[mt][3]);
      *reinterpret_cast<uint2*>(o + mt * 8) = pk;
    }
    if (!has) break;
    #pragma unroll
    for (int kk = 0; kk < 4; ++kk) xc[kk] = xn[kk];
    t = nxt;
  }
}

// ---------------- SpMM gather: 16-lane group per node ------------------------
// 4 nodes/wave, 16 nodes/block. Each lane gathers 16B (8 features) per edge;
// one load instruction touches 4 distinct rows (16 lines) -> 4x the MLP of the
// old one-node-per-wave layout. rv entries loaded coalesced per 16-lane chunk,
// broadcast via __shfl.
// MODE 0: bias build  Bb += gather (no relu), write Bb packed bf16
// MODE 1: iteration   relu(gather + Bb) -> Xb packed bf16
// MODE 2: last iter   relu(gather + Bb) -> Xf fp32
template<int MODE>
__global__ __launch_bounds__(256, 8)
void spmm_k(const int* __restrict__ colptr, const uint2* __restrict__ rv,
            const u16* __restrict__ Src, u32* __restrict__ Bb,
            u32* __restrict__ Xb, float* __restrict__ Xf) {
  int wid = threadIdx.x >> 6;
  int lane = threadIdx.x & 63;
  int l16 = lane & 15;
  int gb = lane & 48;                      // group base lane (g*16)
  int n = blockIdx.x * 16 + wid * 4 + (lane >> 4);
  int beg = colptr[n];
  int deg = colptr[n + 1] - beg;
  const u32* sp = (const u32*)Src + l16 * 4;
  float a0 = 0.f, a1 = 0.f, a2 = 0.f, a3 = 0.f;
  float a4 = 0.f, a5 = 0.f, a6 = 0.f, a7 = 0.f;
  for (int base = 0; base < deg; base += 16) {
    int cnt = deg - base; if (cnt > 16) cnt = 16;
    uint2 p = rv[beg + base + ((l16 < cnt) ? l16 : 0)];
    int rr = (int)p.x;
    float vv = __uint_as_float(p.y);
    int j = 0;
    for (; j + 4 <= cnt; j += 4) {
      int ri[4]; float vi[4]; uint4 xr[4];
      #pragma unroll
      for (int q = 0; q < 4; ++q) ri[q] = __shfl(rr, gb + j + q);
      #pragma unroll
      for (int q = 0; q < 4; ++q)
        xr[q] = *(const uint4*)(sp + (size_t)ri[q] * 64);
      #pragma unroll
      for (int q = 0; q < 4; ++q) vi[q] = __shfl(vv, gb + j + q);
      #pragma unroll
      for (int q = 0; q < 4; ++q) {
        a0 += vi[q] * bflo(xr[q].x); a1 += vi[q] * bfhi(xr[q].x);
        a2 += vi[q] * bflo(xr[q].y); a3 += vi[q] * bfhi(xr[q].y);
        a4 += vi[q] * bflo(xr[q].z); a5 += vi[q] * bfhi(xr[q].z);
        a6 += vi[q] * bflo(xr[q].w); a7 += vi[q] * bfhi(xr[q].w);
      }
    }
    for (; j < cnt; ++j) {
      int re = __shfl(rr, gb + j);
      float ve = __shfl(vv, gb + j);
      uint4 x = *(const uint4*)(sp + (size_t)re * 64);
      a0 += ve * bflo(x.x); a1 += ve * bfhi(x.x);
      a2 += ve * bflo(x.y); a3 += ve * bfhi(x.y);
      a4 += ve * bflo(x.z); a5 += ve * bfhi(x.z);
      a6 += ve * bflo(x.w); a7 += ve * bfhi(x.w);
    }
  }
  uint4 bp = *(const uint4*)(Bb + (size_t)n * 64 + l16 * 4);
  float o0 = a0 + bflo(bp.x), o1 = a1 + bfhi(bp.x);
  float o2 = a2 + bflo(bp.y), o3 = a3 + bfhi(bp.y);
  float o4 = a4 + bflo(bp.z), o5 = a5 + bfhi(bp.z);
  float o6 = a6 + bflo(bp.w), o7 = a7 + bfhi(bp.w);
  if (MODE >= 1) {
    o0 = fmaxf(o0, 0.f); o1 = fmaxf(o1, 0.f);
    o2 = fmaxf(o2, 0.f); o3 = fmaxf(o3, 0.f);
    o4 = fmaxf(o4, 0.f); o5 = fmaxf(o5, 0.f);
    o6 = fmaxf(o6, 0.f); o7 = fmaxf(o7, 0.f);
  }
  if (MODE <= 1) {
    uint4 pk;
    pk.x = pack2bf(o0, o1); pk.y = pack2bf(o2, o3);
    pk.z = pack2bf(o4, o5); pk.w = pack2bf(o6, o7);
    u32* dst = (MODE == 0) ? Bb : Xb;
    *(uint4*)(dst + (size_t)n * 64 + l16 * 4) = pk;
  } else {
    float* xo = Xf + (size_t)n * 128 + l16 * 8;
    *(float4*)(xo)     = make_float4(o0, o1, o2, o3);
    *(float4*)(xo + 4) = make_float4(o4, o5, o6, o7);
  }
}

// ---------------- Xf (N x 128 f32) -> out (128 x N f32) ----------------------
__global__ __launch_bounds__(256)
void transpose_out(const float* __restrict__ Xf, float* __restrict__ out, int Nn) {
  __shared__ float sh[128][65];
  int n0 = blockIdx.x * 64;
  int t = threadIdx.x;
  #pragma unroll
  for (int i = 0; i < 32; ++i) {
    int idx = i * 256 + t;
    int node = idx >> 7, m = idx & 127;
    int n = n0 + node;
    float v = (n < Nn) ? Xf[(size_t)n * 128 + m] : 0.f;
    sh[m][node] = v;
  }
  __syncthreads();
  #pragma unroll
  for (int i = 0; i < 32; ++i) {
    int idx = i * 256 + t;
    int m = idx >> 6, nl = idx & 63;
    int n = n0 + nl;
    if (n < Nn) out[(size_t)m * Nn + n] = sh[m][nl];
  }
}

// ---------------- launcher ---------------------------------------------------
extern "C" void kernel_launch(void* const* d_in, const int* in_sizes, int n_in,
                              void* d_out, int out_size, void* d_ws, size_t ws_size,
                              hipStream_t stream) {
  (void)in_sizes; (void)n_in; (void)out_size; (void)ws_size;
  const float* U   = (const float*)d_in[0];
  const int*   er  = (const int*)d_in[1];
  const int*   ec  = (const int*)d_in[2];
  const float* ev  = (const float*)d_in[3];
  const float* W   = (const float*)d_in[4];
  const float* Om1 = (const float*)d_in[5];
  const float* Om2 = (const float*)d_in[6];
  float* out = (float*)d_out;

  char* base = (char*)d_ws;
  size_t off = 0;
  auto alloc = [&](size_t b) {
    char* p = base + off;
    off = (off + b + 255) & ~(size_t)255;
    return p;
  };
  u16* Wb     = (u16*)alloc(128 * 128 * 2);
  u16* Om1b   = (u16*)alloc(128 * 128 * 2);
  u16* Om2b   = (u16*)alloc(128 * 128 * 2);
  float* Xf   = (float*)alloc((size_t)NN * 128 * 4);  // aliased: Ub lives here
  u16* Ub     = (u16*)Xf;                             // Ub dead before Xf written
  u32* Xb     = (u32*)alloc((size_t)NN * 64 * 4);
  u32* Xwb    = (u32*)alloc((size_t)NN * 64 * 4);
  u32* Bb     = (u32*)alloc((size_t)NN * 64 * 4);
  int* counts = (int*)alloc((size_t)NN * 4);
  int* colptr = (int*)alloc((size_t)(NN + 1) * 4);
  int* cursor = (int*)alloc((size_t)NN * 4);
  int* bsums  = (int*)alloc((size_t)NB1 * 4);
  int* boffs  = (int*)alloc((size_t)NB1 * 4);
  uint2* rv   = (uint2*)alloc((size_t)EE * 8);

  // setup: projection, converts, transpose, CSC build
  proj_w<<<dim3(128), dim3(128), 0, stream>>>(W, Wb);
  convert_mat2<<<dim3(128), dim3(256), 0, stream>>>(Om1, Om2, Om1b, Om2b);
  transpose_u<<<dim3((NN + 63) / 64), dim3(256), 0, stream>>>(U, Ub, NN);
  hipMemsetAsync(counts, 0, (size_t)NN * 4, stream);
  hist_k<<<dim3(EE / 256), dim3(256), 0, stream>>>(ec, counts);
  scan1<<<dim3(NB1), dim3(256), 0, stream>>>(counts, bsums);
  scan2<<<dim3(1), dim3(256), 0, stream>>>(bsums, boffs);
  scan3<<<dim3(NB1), dim3(256), 0, stream>>>(counts, boffs, colptr, cursor);
  scatter_k<<<dim3(SC_PASSES * SC_BLOCKS), dim3(256), 0, stream>>>(er, ec, ev, cursor, rv);

  // B = gather(Omega_1 @ U) + Omega_2 @ U  (Bb holds bf16 B); X_0 = B
  gemm_k<<<dim3(512), dim3(256), 0, stream>>>(Om1b, Ub, Xwb);
  gemm_k<<<dim3(512), dim3(256), 0, stream>>>(Om2b, Ub, Bb);
  spmm_k<0><<<dim3(NN / 16), dim3(256), 0, stream>>>(colptr, rv, (const u16*)Xwb,
                                                     Bb, (u32*)nullptr, (float*)nullptr);

  // 20 fixed-point iterations (X_0 = B lives in Bb for the first gemm)
  for (int it = 0; it < ITERS; ++it) {
    const u16* xsrc = (it == 0) ? (const u16*)Bb : (const u16*)Xb;
    gemm_k<<<dim3(512), dim3(256), 0, stream>>>(Wb, xsrc, Xwb);
    if (it < ITERS - 1)
      spmm_k<1><<<dim3(NN / 16), dim3(256), 0, stream>>>(colptr, rv, (const u16*)Xwb,
                                                         Bb, Xb, (float*)nullptr);
    else
      spmm_k<2><<<dim3(NN / 16), dim3(256), 0, stream>>>(colptr, rv, (const u16*)Xwb,
                                                         Bb, (u32*)nullptr, Xf);
  }

  transpose_out<<<dim3((NN + 63) / 64), dim3(256), 0, stream>>>(Xf, out, NN);
}

// Round 6
// 1210.813 us; speedup vs baseline: 1.2600x; 1.0086x over previous
//
#include <hip/hip_runtime.h>

#define NN 50000
#define EE 800000
#define ITERS 20
#define KAPPA 0.99f
#define NTILES 3125   // NN/16
#define NB1 196       // ceil(NN/256)
#define SC_PASSES 8
#define SC_BLOCKS (EE / 256)   // 3125
#define SC_RANGE (NN / SC_PASSES) // 6250

typedef __bf16 bf16x8 __attribute__((ext_vector_type(8)));
typedef float f32x4 __attribute__((ext_vector_type(4)));
typedef unsigned short u16;
typedef unsigned int u32;

__device__ __forceinline__ u16 f2bf(float f) {
  u32 u = __float_as_uint(f);
  u32 r = u + 0x7FFFu + ((u >> 16) & 1u);
  return (u16)(r >> 16);
}
__device__ __forceinline__ u32 pack2bf(float a, float b) {
  return (u32)f2bf(a) | ((u32)f2bf(b) << 16);
}
__device__ __forceinline__ float bflo(u32 x) { return __uint_as_float(x << 16); }
__device__ __forceinline__ float bfhi(u32 x) { return __uint_as_float(x & 0xFFFF0000u); }

// ---------------- W projection (rows onto l1-ball of radius kappa) -> bf16 ----
__global__ __launch_bounds__(128)
void proj_w(const float* __restrict__ W, u16* __restrict__ Wb) {
  __shared__ float su[128];
  __shared__ float scs[128];
  __shared__ int sred[128];
  __shared__ float theta_s, rowsum_s;
  int row = blockIdx.x, t = threadIdx.x;
  float w = W[row * 128 + t];
  float aw = fabsf(w);
  su[t] = aw;
  __syncthreads();
  for (int k = 2; k <= 128; k <<= 1) {
    for (int j = k >> 1; j > 0; j >>= 1) {
      int ixj = t ^ j;
      if (ixj > t) {
        float a = su[t], b = su[ixj];
        if ((t & k) == 0) { if (a > b) { su[t] = b; su[ixj] = a; } }
        else              { if (a < b) { su[t] = b; su[ixj] = a; } }
      }
      __syncthreads();
    }
  }
  float ud = su[127 - t];
  scs[t] = ud;
  __syncthreads();
  for (int off = 1; off < 128; off <<= 1) {
    float v = (t >= off) ? scs[t - off] : 0.f;
    __syncthreads();
    scs[t] += v;
    __syncthreads();
  }
  float cs = scs[t] - KAPPA;
  sred[t] = ((ud - cs / (float)(t + 1)) > 0.f) ? 1 : 0;
  __syncthreads();
  for (int off = 64; off > 0; off >>= 1) {
    if (t < off) sred[t] += sred[t + off];
    __syncthreads();
  }
  if (t == 0) {
    int rho = sred[0] - 1;
    float th = (scs[rho] - KAPPA) / (float)(rho + 1);
    theta_s = fmaxf(th, 0.f);
    rowsum_s = scs[127];
  }
  __syncthreads();
  float outv;
  if (rowsum_s > KAPPA) {
    float pw = fmaxf(aw - theta_s, 0.f);
    outv = (w >= 0.f) ? pw : -pw;
  } else {
    outv = w;
  }
  Wb[row * 128 + t] = f2bf(outv);
}

// ---------------- two small f32 -> bf16 converts fused -----------------------
__global__ __launch_bounds__(256)
void convert_mat2(const float* __restrict__ a, const float* __restrict__ b,
                  u16* __restrict__ oa, u16* __restrict__ ob) {
  int i = blockIdx.x * 256 + threadIdx.x;
  if (i < 16384) oa[i] = f2bf(a[i]);
  else           ob[i - 16384] = f2bf(b[i - 16384]);
}

// ---------------- U (128 x N) -> Ub (N x 128 bf16) ---------------------------
__global__ __launch_bounds__(256)
void transpose_u(const float* __restrict__ U, u16* __restrict__ Ub, int Nn) {
  __shared__ u16 sh[64][130];
  int n0 = blockIdx.x * 64;
  int t = threadIdx.x;
  int nl = t & 63, pq = t >> 6;
  #pragma unroll
  for (int i = 0; i < 128; i += 4) {
    int p = i + pq;
    int n = n0 + nl;
    float v = (n < Nn) ? U[(size_t)p * Nn + n] : 0.f;
    sh[nl][p] = f2bf(v);
  }
  __syncthreads();
  #pragma unroll
  for (int j = 0; j < 16; ++j) {
    int node = j * 4 + pq;
    int n = n0 + node;
    if (n < Nn) {
      u32 lo = sh[node][nl * 2], hi = sh[node][nl * 2 + 1];
      ((u32*)Ub)[(size_t)n * 64 + nl] = lo | (hi << 16);
    }
  }
}

// ---------------- CSC build --------------------------------------------------
__global__ __launch_bounds__(256)
void hist_k(const int* __restrict__ cols, int* __restrict__ counts) {
  int i = blockIdx.x * 256 + threadIdx.x;
  atomicAdd(&counts[cols[i]], 1);
}

// decoupled 3-kernel scan (all coalesced)
__global__ __launch_bounds__(256)
void scan1(const int* __restrict__ counts, int* __restrict__ bsums) {
  __shared__ int s[256];
  int t = threadIdx.x;
  int i = blockIdx.x * 256 + t;
  s[t] = (i < NN) ? counts[i] : 0;
  __syncthreads();
  for (int off = 128; off > 0; off >>= 1) {
    if (t < off) s[t] += s[t + off];
    __syncthreads();
  }
  if (t == 0) bsums[blockIdx.x] = s[0];
}

__global__ __launch_bounds__(256)
void scan2(const int* __restrict__ bsums, int* __restrict__ boffs) {
  __shared__ int s[256];
  int t = threadIdx.x;
  int v = (t < NB1) ? bsums[t] : 0;
  s[t] = v;
  __syncthreads();
  for (int off = 1; off < 256; off <<= 1) {
    int u = (t >= off) ? s[t - off] : 0;
    __syncthreads();
    s[t] += u;
    __syncthreads();
  }
  if (t < NB1) boffs[t] = s[t] - v;   // exclusive
}

__global__ __launch_bounds__(256)
void scan3(const int* __restrict__ counts, const int* __restrict__ boffs,
           int* __restrict__ colptr, int* __restrict__ cursor) {
  __shared__ int s[256];
  int t = threadIdx.x;
  int i = blockIdx.x * 256 + t;
  int v = (i < NN) ? counts[i] : 0;
  s[t] = v;
  __syncthreads();
  for (int off = 1; off < 256; off <<= 1) {
    int u = (t >= off) ? s[t - off] : 0;
    __syncthreads();
    s[t] += u;
    __syncthreads();
  }
  int excl = s[t] - v + boffs[blockIdx.x];
  if (i < NN) { colptr[i] = excl; cursor[i] = excl; }
  if (i == 0) colptr[NN] = EE;
}

// 8 column-range passes, XCD-aligned: pass = blockIdx & 7 so (with the
// round-robin block->XCD dispatch) each pass runs on ONE XCD and its 800 KB
// rv window stays in that XCD's private L2 -> writebacks collapse.
__global__ __launch_bounds__(256)
void scatter_k(const int* __restrict__ rows, const int* __restrict__ cols,
               const float* __restrict__ vals, int* __restrict__ cursor,
               uint2* __restrict__ rv) {
  int pass = blockIdx.x & 7;
  int i = (blockIdx.x >> 3) * 256 + threadIdx.x;
  int c = cols[i];
  int lo = pass * SC_RANGE;
  if (c >= lo && c < lo + SC_RANGE) {
    int pos = atomicAdd(&cursor[c], 1);
    rv[pos] = make_uint2((u32)rows[i], __float_as_uint(vals[i]));
  }
}

// ---------------- GEMM: out[n][m] = sum_k Mat[m][k] * Xsrc[n][k] -------------
// Swapped MFMA; 1-deep software prefetch of the next X tile across the
// grid-stride loop. Output packed bf16 (u32 pairs).
__global__ __launch_bounds__(256, 2)
void gemm_k(const u16* __restrict__ Mb, const u16* __restrict__ Xsrc,
            u32* __restrict__ outp) {
  int lane = threadIdx.x & 63;
  int wid = threadIdx.x >> 6;
  int r = lane & 15, kg = lane >> 4;
  bf16x8 wf[8][4];
  #pragma unroll
  for (int mt = 0; mt < 8; ++mt)
    #pragma unroll
    for (int kk = 0; kk < 4; ++kk)
      wf[mt][kk] = *reinterpret_cast<const bf16x8*>(
          Mb + (mt * 16 + r) * 128 + kk * 32 + kg * 8);
  const int nw = gridDim.x * 4;
  int t = blockIdx.x * 4 + wid;
  if (t >= NTILES) return;
  bf16x8 xc[4], xn[4];
  {
    const u16* xp = Xsrc + (size_t)(t * 16 + r) * 128 + kg * 8;
    #pragma unroll
    for (int kk = 0; kk < 4; ++kk)
      xc[kk] = *reinterpret_cast<const bf16x8*>(xp + kk * 32);
  }
  while (true) {
    int nxt = t + nw;
    bool has = (nxt < NTILES);
    if (has) {
      const u16* xp = Xsrc + (size_t)(nxt * 16 + r) * 128 + kg * 8;
      #pragma unroll
      for (int kk = 0; kk < 4; ++kk)
        xn[kk] = *reinterpret_cast<const bf16x8*>(xp + kk * 32);
    }
    f32x4 acc[8];
    #pragma unroll
    for (int mt = 0; mt < 8; ++mt) acc[mt] = (f32x4)(0.f);
    #pragma unroll
    for (int mt = 0; mt < 8; ++mt)
      #pragma unroll
      for (int kk = 0; kk < 4; ++kk)
        acc[mt] = __builtin_amdgcn_mfma_f32_16x16x32_bf16(
            wf[mt][kk], xc[kk], acc[mt], 0, 0, 0);
    u32* o = outp + (size_t)(t * 16 + r) * 64 + kg * 2;
    #pragma unroll
    for (int mt = 0; mt < 8; ++mt) {
      uint2 pk;
      pk.x = pack2bf(acc[mt][0], acc[mt][1]);
      pk.y = pack2bf(acc[mt][2], acc[mt][3]);
      *reinterpret_cast<uint2*>(o + mt * 8) = pk;
    }
    if (!has) break;
    #pragma unroll
    for (int kk = 0; kk < 4; ++kk) xc[kk] = xn[kk];
    t = nxt;
  }
}

// ---------------- SpMM gather: 16-lane group per node ------------------------
// 4 nodes/wave. Per 16-edge chunk: rv loaded coalesced, then up to 2 blocks of
// 8 back-to-back uint4 gathers (8 loads in flight, predicated v past cnt).
// B-row load hoisted before the gather loop.
// MODE 0: bias build  Bb += gather (no relu), write Bb packed bf16
// MODE 1: iteration   relu(gather + Bb) -> Xb packed bf16
// MODE 2: last iter   relu(gather + Bb) -> Xf fp32
template<int MODE>
__global__ __launch_bounds__(256, 4)
void spmm_k(const int* __restrict__ colptr, const uint2* __restrict__ rv,
            const u16* __restrict__ Src, u32* __restrict__ Bb,
            u32* __restrict__ Xb, float* __restrict__ Xf) {
  int wid = threadIdx.x >> 6;
  int lane = threadIdx.x & 63;
  int l16 = lane & 15;
  int gb = lane & 48;                      // group base lane (g*16)
  int n = blockIdx.x * 16 + wid * 4 + (lane >> 4);
  int beg = colptr[n];
  int deg = colptr[n + 1] - beg;
  const u32* sp = (const u32*)Src + l16 * 4;
  uint4 bp = *(const uint4*)(Bb + (size_t)n * 64 + l16 * 4);  // hoisted
  float a0 = 0.f, a1 = 0.f, a2 = 0.f, a3 = 0.f;
  float a4 = 0.f, a5 = 0.f, a6 = 0.f, a7 = 0.f;
  for (int base = 0; base < deg; base += 16) {
    int cnt = deg - base; if (cnt > 16) cnt = 16;
    uint2 p = rv[beg + base + ((l16 < cnt) ? l16 : 0)];
    int rr = (int)p.x;
    float vv = __uint_as_float(p.y);
    #pragma unroll
    for (int h = 0; h < 2; ++h) {
      int j0 = h * 8;
      if (j0 < cnt) {
        int ri[8]; float vi[8]; uint4 xr[8];
        #pragma unroll
        for (int q = 0; q < 8; ++q) ri[q] = __shfl(rr, gb + j0 + q);
        #pragma unroll
        for (int q = 0; q < 8; ++q)
          xr[q] = *(const uint4*)(sp + (size_t)ri[q] * 64);
        #pragma unroll
        for (int q = 0; q < 8; ++q) {
          float f = __shfl(vv, gb + j0 + q);
          vi[q] = (j0 + q < cnt) ? f : 0.f;
        }
        #pragma unroll
        for (int q = 0; q < 8; ++q) {
          a0 += vi[q] * bflo(xr[q].x); a1 += vi[q] * bfhi(xr[q].x);
          a2 += vi[q] * bflo(xr[q].y); a3 += vi[q] * bfhi(xr[q].y);
          a4 += vi[q] * bflo(xr[q].z); a5 += vi[q] * bfhi(xr[q].z);
          a6 += vi[q] * bflo(xr[q].w); a7 += vi[q] * bfhi(xr[q].w);
        }
      }
    }
  }
  float o0 = a0 + bflo(bp.x), o1 = a1 + bfhi(bp.x);
  float o2 = a2 + bflo(bp.y), o3 = a3 + bfhi(bp.y);
  float o4 = a4 + bflo(bp.z), o5 = a5 + bfhi(bp.z);
  float o6 = a6 + bflo(bp.w), o7 = a7 + bfhi(bp.w);
  if (MODE >= 1) {
    o0 = fmaxf(o0, 0.f); o1 = fmaxf(o1, 0.f);
    o2 = fmaxf(o2, 0.f); o3 = fmaxf(o3, 0.f);
    o4 = fmaxf(o4, 0.f); o5 = fmaxf(o5, 0.f);
    o6 = fmaxf(o6, 0.f); o7 = fmaxf(o7, 0.f);
  }
  if (MODE <= 1) {
    uint4 pk;
    pk.x = pack2bf(o0, o1); pk.y = pack2bf(o2, o3);
    pk.z = pack2bf(o4, o5); pk.w = pack2bf(o6, o7);
    u32* dst = (MODE == 0) ? Bb : Xb;
    *(uint4*)(dst + (size_t)n * 64 + l16 * 4) = pk;
  } else {
    float* xo = Xf + (size_t)n * 128 + l16 * 8;
    *(float4*)(xo)     = make_float4(o0, o1, o2, o3);
    *(float4*)(xo + 4) = make_float4(o4, o5, o6, o7);
  }
}

// ---------------- Xf (N x 128 f32) -> out (128 x N f32) ----------------------
__global__ __launch_bounds__(256)
void transpose_out(const float* __restrict__ Xf, float* __restrict__ out, int Nn) {
  __shared__ float sh[128][65];
  int n0 = blockIdx.x * 64;
  int t = threadIdx.x;
  #pragma unroll
  for (int i = 0; i < 32; ++i) {
    int idx = i * 256 + t;
    int node = idx >> 7, m = idx & 127;
    int n = n0 + node;
    float v = (n < Nn) ? Xf[(size_t)n * 128 + m] : 0.f;
    sh[m][node] = v;
  }
  __syncthreads();
  #pragma unroll
  for (int i = 0; i < 32; ++i) {
    int idx = i * 256 + t;
    int m = idx >> 6, nl = idx & 63;
    int n = n0 + nl;
    if (n < Nn) out[(size_t)m * Nn + n] = sh[m][nl];
  }
}

// ---------------- launcher ---------------------------------------------------
extern "C" void kernel_launch(void* const* d_in, const int* in_sizes, int n_in,
                              void* d_out, int out_size, void* d_ws, size_t ws_size,
                              hipStream_t stream) {
  (void)in_sizes; (void)n_in; (void)out_size; (void)ws_size;
  const float* U   = (const float*)d_in[0];
  const int*   er  = (const int*)d_in[1];
  const int*   ec  = (const int*)d_in[2];
  const float* ev  = (const float*)d_in[3];
  const float* W   = (const float*)d_in[4];
  const float* Om1 = (const float*)d_in[5];
  const float* Om2 = (const float*)d_in[6];
  float* out = (float*)d_out;

  char* base = (char*)d_ws;
  size_t off = 0;
  auto alloc = [&](size_t b) {
    char* p = base + off;
    off = (off + b + 255) & ~(size_t)255;
    return p;
  };
  u16* Wb     = (u16*)alloc(128 * 128 * 2);
  u16* Om1b   = (u16*)alloc(128 * 128 * 2);
  u16* Om2b   = (u16*)alloc(128 * 128 * 2);
  float* Xf   = (float*)alloc((size_t)NN * 128 * 4);  // aliased: Ub lives here
  u16* Ub     = (u16*)Xf;                             // Ub dead before Xf written
  u32* Xb     = (u32*)alloc((size_t)NN * 64 * 4);
  u32* Xwb    = (u32*)alloc((size_t)NN * 64 * 4);
  u32* Bb     = (u32*)alloc((size_t)NN * 64 * 4);
  int* counts = (int*)alloc((size_t)NN * 4);
  int* colptr = (int*)alloc((size_t)(NN + 1) * 4);
  int* cursor = (int*)alloc((size_t)NN * 4);
  int* bsums  = (int*)alloc((size_t)NB1 * 4);
  int* boffs  = (int*)alloc((size_t)NB1 * 4);
  uint2* rv   = (uint2*)alloc((size_t)EE * 8);

  // setup: projection, converts, transpose, CSC build
  proj_w<<<dim3(128), dim3(128), 0, stream>>>(W, Wb);
  convert_mat2<<<dim3(128), dim3(256), 0, stream>>>(Om1, Om2, Om1b, Om2b);
  transpose_u<<<dim3((NN + 63) / 64), dim3(256), 0, stream>>>(U, Ub, NN);
  hipMemsetAsync(counts, 0, (size_t)NN * 4, stream);
  hist_k<<<dim3(EE / 256), dim3(256), 0, stream>>>(ec, counts);
  scan1<<<dim3(NB1), dim3(256), 0, stream>>>(counts, bsums);
  scan2<<<dim3(1), dim3(256), 0, stream>>>(bsums, boffs);
  scan3<<<dim3(NB1), dim3(256), 0, stream>>>(counts, boffs, colptr, cursor);
  scatter_k<<<dim3(SC_PASSES * SC_BLOCKS), dim3(256), 0, stream>>>(er, ec, ev, cursor, rv);

  // B = gather(Omega_1 @ U) + Omega_2 @ U  (Bb holds bf16 B); X_0 = B
  gemm_k<<<dim3(512), dim3(256), 0, stream>>>(Om1b, Ub, Xwb);
  gemm_k<<<dim3(512), dim3(256), 0, stream>>>(Om2b, Ub, Bb);
  spmm_k<0><<<dim3(NN / 16), dim3(256), 0, stream>>>(colptr, rv, (const u16*)Xwb,
                                                     Bb, (u32*)nullptr, (float*)nullptr);

  // 20 fixed-point iterations (X_0 = B lives in Bb for the first gemm)
  for (int it = 0; it < ITERS; ++it) {
    const u16* xsrc = (it == 0) ? (const u16*)Bb : (const u16*)Xb;
    gemm_k<<<dim3(512), dim3(256), 0, stream>>>(Wb, xsrc, Xwb);
    if (it < ITERS - 1)
      spmm_k<1><<<dim3(NN / 16), dim3(256), 0, stream>>>(colptr, rv, (const u16*)Xwb,
                                                         Bb, Xb, (float*)nullptr);
    else
      spmm_k<2><<<dim3(NN / 16), dim3(256), 0, stream>>>(colptr, rv, (const u16*)Xwb,
                                                         Bb, (u32*)nullptr, Xf);
  }

  transpose_out<<<dim3((NN + 63) / 64), dim3(256), 0, stream>>>(Xf, out, NN);
}

// Round 10
// 1210.538 us; speedup vs baseline: 1.2603x; 1.0002x over previous
//
#include <hip/hip_runtime.h>

#define NN 50000
#define EE 800000
#define ITERS 20
#define KAPPA 0.99f
#define NTILES 3125        // NN/16
#define NCHUNK 4
#define CHROWS 12500       // NN/NCHUNK rows per chunk (3.2 MB bf16 <= 4MiB L2)
#define NV (NN * NCHUNK)   // virtual columns
#define NB2 782            // ceil(NV/256)
#define SC_VRANGE (NV / 8) // 25000 vcols per scatter pass

typedef __bf16 bf16x8 __attribute__((ext_vector_type(8)));
typedef float f32x4 __attribute__((ext_vector_type(4)));
typedef unsigned short u16;
typedef unsigned int u32;

__device__ __forceinline__ u16 f2bf(float f) {
  u32 u = __float_as_uint(f);
  u32 r = u + 0x7FFFu + ((u >> 16) & 1u);
  return (u16)(r >> 16);
}
__device__ __forceinline__ u32 pack2bf(float a, float b) {
  return (u32)f2bf(a) | ((u32)f2bf(b) << 16);
}
__device__ __forceinline__ float bflo(u32 x) { return __uint_as_float(x << 16); }
__device__ __forceinline__ float bfhi(u32 x) { return __uint_as_float(x & 0xFFFF0000u); }

// ---------------- W projection (rows onto l1-ball of radius kappa) -> bf16 ----
__global__ __launch_bounds__(128)
void proj_w(const float* __restrict__ W, u16* __restrict__ Wb) {
  __shared__ float su[128];
  __shared__ float scs[128];
  __shared__ int sred[128];
  __shared__ float theta_s, rowsum_s;
  int row = blockIdx.x, t = threadIdx.x;
  float w = W[row * 128 + t];
  float aw = fabsf(w);
  su[t] = aw;
  __syncthreads();
  for (int k = 2; k <= 128; k <<= 1) {
    for (int j = k >> 1; j > 0; j >>= 1) {
      int ixj = t ^ j;
      if (ixj > t) {
        float a = su[t], b = su[ixj];
        if ((t & k) == 0) { if (a > b) { su[t] = b; su[ixj] = a; } }
        else              { if (a < b) { su[t] = b; su[ixj] = a; } }
      }
      __syncthreads();
    }
  }
  float ud = su[127 - t];
  scs[t] = ud;
  __syncthreads();
  for (int off = 1; off < 128; off <<= 1) {
    float v = (t >= off) ? scs[t - off] : 0.f;
    __syncthreads();
    scs[t] += v;
    __syncthreads();
  }
  float cs = scs[t] - KAPPA;
  sred[t] = ((ud - cs / (float)(t + 1)) > 0.f) ? 1 : 0;
  __syncthreads();
  for (int off = 64; off > 0; off >>= 1) {
    if (t < off) sred[t] += sred[t + off];
    __syncthreads();
  }
  if (t == 0) {
    int rho = sred[0] - 1;
    float th = (scs[rho] - KAPPA) / (float)(rho + 1);
    theta_s = fmaxf(th, 0.f);
    rowsum_s = scs[127];
  }
  __syncthreads();
  float outv;
  if (rowsum_s > KAPPA) {
    float pw = fmaxf(aw - theta_s, 0.f);
    outv = (w >= 0.f) ? pw : -pw;
  } else {
    outv = w;
  }
  Wb[row * 128 + t] = f2bf(outv);
}

// ---------------- two small f32 -> bf16 converts fused -----------------------
__global__ __launch_bounds__(256)
void convert_mat2(const float* __restrict__ a, const float* __restrict__ b,
                  u16* __restrict__ oa, u16* __restrict__ ob) {
  int i = blockIdx.x * 256 + threadIdx.x;
  if (i < 16384) oa[i] = f2bf(a[i]);
  else           ob[i - 16384] = f2bf(b[i - 16384]);
}

// ---------------- U (128 x N) -> Ub (N x 128 bf16) ---------------------------
__global__ __launch_bounds__(256)
void transpose_u(const float* __restrict__ U, u16* __restrict__ Ub, int Nn) {
  __shared__ u16 sh[64][130];
  int n0 = blockIdx.x * 64;
  int t = threadIdx.x;
  int nl = t & 63, pq = t >> 6;
  #pragma unroll
  for (int i = 0; i < 128; i += 4) {
    int p = i + pq;
    int n = n0 + nl;
    float v = (n < Nn) ? U[(size_t)p * Nn + n] : 0.f;
    sh[nl][p] = f2bf(v);
  }
  __syncthreads();
  #pragma unroll
  for (int j = 0; j < 16; ++j) {
    int node = j * 4 + pq;
    int n = n0 + node;
    if (n < Nn) {
      u32 lo = sh[node][nl * 2], hi = sh[node][nl * 2 + 1];
      ((u32*)Ub)[(size_t)n * 64 + nl] = lo | (hi << 16);
    }
  }
}

// ---------------- chunked-CSC build ------------------------------------------
// Virtual column vcol = col*4 + row/CHROWS. Edges of one node end up grouped
// by row-chunk; all spmm blocks then walk chunks in the same order, keeping
// the concurrently-gathered row set ~3.2MB (L2-resident per XCD).
__global__ __launch_bounds__(256)
void hist_k(const int* __restrict__ rows, const int* __restrict__ cols,
            int* __restrict__ counts) {
  int i = blockIdx.x * 256 + threadIdx.x;
  u32 vc = (u32)cols[i] * NCHUNK + (u32)rows[i] / CHROWS;
  atomicAdd(&counts[vc], 1);
}

// decoupled 3-kernel scan over NV counters (all coalesced)
__global__ __launch_bounds__(256)
void scan1(const int* __restrict__ counts, int* __restrict__ bsums) {
  __shared__ int s[256];
  int t = threadIdx.x;
  int i = blockIdx.x * 256 + t;
  s[t] = (i < NV) ? counts[i] : 0;
  __syncthreads();
  for (int off = 128; off > 0; off >>= 1) {
    if (t < off) s[t] += s[t + off];
    __syncthreads();
  }
  if (t == 0) bsums[blockIdx.x] = s[0];
}

__global__ __launch_bounds__(1024)
void scan2(const int* __restrict__ bsums, int* __restrict__ boffs) {
  __shared__ int s[1024];
  int t = threadIdx.x;
  int v = (t < NB2) ? bsums[t] : 0;
  s[t] = v;
  __syncthreads();
  for (int off = 1; off < 1024; off <<= 1) {
    int u = (t >= off) ? s[t - off] : 0;
    __syncthreads();
    s[t] += u;
    __syncthreads();
  }
  if (t < NB2) boffs[t] = s[t] - v;   // exclusive
}

__global__ __launch_bounds__(256)
void scan3(const int* __restrict__ counts, const int* __restrict__ boffs,
           int* __restrict__ colptr, int* __restrict__ cursor) {
  __shared__ int s[256];
  int t = threadIdx.x;
  int i = blockIdx.x * 256 + t;
  int v = (i < NV) ? counts[i] : 0;
  s[t] = v;
  __syncthreads();
  for (int off = 1; off < 256; off <<= 1) {
    int u = (t >= off) ? s[t - off] : 0;
    __syncthreads();
    s[t] += u;
    __syncthreads();
  }
  int excl = s[t] - v + boffs[blockIdx.x];
  if (i < NV) { colptr[i] = excl; cursor[i] = excl; }
  if (i == 0) colptr[NV] = EE;
}

// 8 vcol-range passes, XCD-aligned (pass = blockIdx & 7): each pass's ~800KB
// rv window stays in one XCD's private L2.
__global__ __launch_bounds__(256)
void scatter_k(const int* __restrict__ rows, const int* __restrict__ cols,
               const float* __restrict__ vals, int* __restrict__ cursor,
               uint2* __restrict__ rv) {
  int pass = blockIdx.x & 7;
  int i = (blockIdx.x >> 3) * 256 + threadIdx.x;
  int r = rows[i];
  u32 vc = (u32)cols[i] * NCHUNK + (u32)r / CHROWS;
  u32 lo = pass * SC_VRANGE;
  if (vc - lo < SC_VRANGE) {
    int pos = atomicAdd(&cursor[vc], 1);
    rv[pos] = make_uint2((u32)r, __float_as_uint(vals[i]));
  }
}

// ---------------- GEMM: out[n][m] = sum_k Mat[m][k] * Xsrc[n][k] -------------
// Swapped MFMA; 1-deep software prefetch of the next X tile across the
// grid-stride loop. Output packed bf16 (u32 pairs).
__global__ __launch_bounds__(256, 2)
void gemm_k(const u16* __restrict__ Mb, const u16* __restrict__ Xsrc,
            u32* __restrict__ outp) {
  int lane = threadIdx.x & 63;
  int wid = threadIdx.x >> 6;
  int r = lane & 15, kg = lane >> 4;
  bf16x8 wf[8][4];
  #pragma unroll
  for (int mt = 0; mt < 8; ++mt)
    #pragma unroll
    for (int kk = 0; kk < 4; ++kk)
      wf[mt][kk] = *reinterpret_cast<const bf16x8*>(
          Mb + (mt * 16 + r) * 128 + kk * 32 + kg * 8);
  const int nw = gridDim.x * 4;
  int t = blockIdx.x * 4 + wid;
  if (t >= NTILES) return;
  bf16x8 xc[4], xn[4];
  {
    const u16* xp = Xsrc + (size_t)(t * 16 + r) * 128 + kg * 8;
    #pragma unroll
    for (int kk = 0; kk < 4; ++kk)
      xc[kk] = *reinterpret_cast<const bf16x8*>(xp + kk * 32);
  }
  while (true) {
    int nxt = t + nw;
    bool has = (nxt < NTILES);
    if (has) {
      const u16* xp = Xsrc + (size_t)(nxt * 16 + r) * 128 + kg * 8;
      #pragma unroll
      for (int kk = 0; kk < 4; ++kk)
        xn[kk] = *reinterpret_cast<const bf16x8*>(xp + kk * 32);
    }
    f32x4 acc[8];
    #pragma unroll
    for (int mt = 0; mt < 8; ++mt) acc[mt] = (f32x4)(0.f);
    #pragma unroll
    for (int mt = 0; mt < 8; ++mt)
      #pragma unroll
      for (int kk = 0; kk < 4; ++kk)
        acc[mt] = __builtin_amdgcn_mfma_f32_16x16x32_bf16(
            wf[mt][kk], xc[kk], acc[mt], 0, 0, 0);
    u32* o = outp + (size_t)(t * 16 + r) * 64 + kg * 2;
    #pragma unroll
    for (int mt = 0; mt < 8; ++mt) {
      uint2 pk;
      pk.x = pack2bf(acc[mt][0], acc[mt][1]);
      pk.y = pack2bf(acc[mt][2], acc[mt][3]);
      *reinterpret_cast<uint2*>(o + mt * 8) = pk;
    }
    if (!has) break;
    #pragma unroll
    for (int kk = 0; kk < 4; ++kk) xc[kk] = xn[kk];
    t = nxt;
  }
}

// ---------------- SpMM gather: 16-lane group per node ------------------------
// Node n's edges live in [colptr[4n], colptr[4n+4]), already grouped by
// row-chunk (chunked CSC) so gathers walk the X rows chunk-by-chunk.
// MODE 0: bias build  Bb += gather (no relu), write Bb packed bf16
// MODE 1: iteration   relu(gather + Bb) -> Xb packed bf16
// MODE 2: last iter   relu(gather + Bb) -> Xf fp32
template<int MODE>
__global__ __launch_bounds__(256, 4)
void spmm_k(const int* __restrict__ colptr, const uint2* __restrict__ rv,
            const u16* __restrict__ Src, u32* __restrict__ Bb,
            u32* __restrict__ Xb, float* __restrict__ Xf) {
  int wid = threadIdx.x >> 6;
  int lane = threadIdx.x & 63;
  int l16 = lane & 15;
  int gb = lane & 48;                      // group base lane (g*16)
  int n = blockIdx.x * 16 + wid * 4 + (lane >> 4);
  int beg = colptr[n * NCHUNK];
  int deg = colptr[n * NCHUNK + NCHUNK] - beg;
  const u32* sp = (const u32*)Src + l16 * 4;
  uint4 bp = *(const uint4*)(Bb + (size_t)n * 64 + l16 * 4);  // hoisted
  float a0 = 0.f, a1 = 0.f, a2 = 0.f, a3 = 0.f;
  float a4 = 0.f, a5 = 0.f, a6 = 0.f, a7 = 0.f;
  for (int base = 0; base < deg; base += 16) {
    int cnt = deg - base; if (cnt > 16) cnt = 16;
    uint2 p = rv[beg + base + ((l16 < cnt) ? l16 : 0)];
    int rr = (int)p.x;
    float vv = __uint_as_float(p.y);
    #pragma unroll
    for (int h = 0; h < 2; ++h) {
      int j0 = h * 8;
      if (j0 < cnt) {
        int ri[8]; float vi[8]; uint4 xr[8];
        #pragma unroll
        for (int q = 0; q < 8; ++q) ri[q] = __shfl(rr, gb + j0 + q);
        #pragma unroll
        for (int q = 0; q < 8; ++q)
          xr[q] = *(const uint4*)(sp + (size_t)ri[q] * 64);
        #pragma unroll
        for (int q = 0; q < 8; ++q) {
          float f = __shfl(vv, gb + j0 + q);
          vi[q] = (j0 + q < cnt) ? f : 0.f;
        }
        #pragma unroll
        for (int q = 0; q < 8; ++q) {
          a0 += vi[q] * bflo(xr[q].x); a1 += vi[q] * bfhi(xr[q].x);
          a2 += vi[q] * bflo(xr[q].y); a3 += vi[q] * bfhi(xr[q].y);
          a4 += vi[q] * bflo(xr[q].z); a5 += vi[q] * bfhi(xr[q].z);
          a6 += vi[q] * bflo(xr[q].w); a7 += vi[q] * bfhi(xr[q].w);
        }
      }
    }
  }
  float o0 = a0 + bflo(bp.x), o1 = a1 + bfhi(bp.x);
  float o2 = a2 + bflo(bp.y), o3 = a3 + bfhi(bp.y);
  float o4 = a4 + bflo(bp.z), o5 = a5 + bfhi(bp.z);
  float o6 = a6 + bflo(bp.w), o7 = a7 + bfhi(bp.w);
  if (MODE >= 1) {
    o0 = fmaxf(o0, 0.f); o1 = fmaxf(o1, 0.f);
    o2 = fmaxf(o2, 0.f); o3 = fmaxf(o3, 0.f);
    o4 = fmaxf(o4, 0.f); o5 = fmaxf(o5, 0.f);
    o6 = fmaxf(o6, 0.f); o7 = fmaxf(o7, 0.f);
  }
  if (MODE <= 1) {
    uint4 pk;
    pk.x = pack2bf(o0, o1); pk.y = pack2bf(o2, o3);
    pk.z = pack2bf(o4, o5); pk.w = pack2bf(o6, o7);
    u32* dst = (MODE == 0) ? Bb : Xb;
    *(uint4*)(dst + (size_t)n * 64 + l16 * 4) = pk;
  } else {
    float* xo = Xf + (size_t)n * 128 + l16 * 8;
    *(float4*)(xo)     = make_float4(o0, o1, o2, o3);
    *(float4*)(xo + 4) = make_float4(o4, o5, o6, o7);
  }
}

// ---------------- Xf (N x 128 f32) -> out (128 x N f32) ----------------------
__global__ __launch_bounds__(256)
void transpose_out(const float* __restrict__ Xf, float* __restrict__ out, int Nn) {
  __shared__ float sh[128][65];
  int n0 = blockIdx.x * 64;
  int t = threadIdx.x;
  #pragma unroll
  for (int i = 0; i < 32; ++i) {
    int idx = i * 256 + t;
    int node = idx >> 7, m = idx & 127;
    int n = n0 + node;
    float v = (n < Nn) ? Xf[(size_t)n * 128 + m] : 0.f;
    sh[m][node] = v;
  }
  __syncthreads();
  #pragma unroll
  for (int i = 0; i < 32; ++i) {
    int idx = i * 256 + t;
    int m = idx >> 6, nl = idx & 63;
    int n = n0 + nl;
    if (n < Nn) out[(size_t)m * Nn + n] = sh[m][nl];
  }
}

// ---------------- launcher ---------------------------------------------------
extern "C" void kernel_launch(void* const* d_in, const int* in_sizes, int n_in,
                              void* d_out, int out_size, void* d_ws, size_t ws_size,
                              hipStream_t stream) {
  (void)in_sizes; (void)n_in; (void)out_size; (void)ws_size;
  const float* U   = (const float*)d_in[0];
  const int*   er  = (const int*)d_in[1];
  const int*   ec  = (const int*)d_in[2];
  const float* ev  = (const float*)d_in[3];
  const float* W   = (const float*)d_in[4];
  const float* Om1 = (const float*)d_in[5];
  const float* Om2 = (const float*)d_in[6];
  float* out = (float*)d_out;

  char* base = (char*)d_ws;
  size_t off = 0;
  auto alloc = [&](size_t b) {
    char* p = base + off;
    off = (off + b + 255) & ~(size_t)255;
    return p;
  };
  u16* Wb     = (u16*)alloc(128 * 128 * 2);
  u16* Om1b   = (u16*)alloc(128 * 128 * 2);
  u16* Om2b   = (u16*)alloc(128 * 128 * 2);
  float* Xf   = (float*)alloc((size_t)NN * 128 * 4);  // aliased: Ub lives here
  u16* Ub     = (u16*)Xf;                             // Ub dead before Xf written
  u32* Xb     = (u32*)alloc((size_t)NN * 64 * 4);
  u32* Xwb    = (u32*)alloc((size_t)NN * 64 * 4);
  u32* Bb     = (u32*)alloc((size_t)NN * 64 * 4);
  int* counts = (int*)alloc((size_t)NV * 4);
  int* colptr = (int*)alloc((size_t)(NV + 1) * 4);
  int* cursor = (int*)alloc((size_t)NV * 4);
  int* bsums  = (int*)alloc((size_t)NB2 * 4);
  int* boffs  = (int*)alloc((size_t)NB2 * 4);
  uint2* rv   = (uint2*)alloc((size_t)EE * 8);

  // setup: projection, converts, transpose, chunked-CSC build
  proj_w<<<dim3(128), dim3(128), 0, stream>>>(W, Wb);
  convert_mat2<<<dim3(128), dim3(256), 0, stream>>>(Om1, Om2, Om1b, Om2b);
  transpose_u<<<dim3((NN + 63) / 64), dim3(256), 0, stream>>>(U, Ub, NN);
  hipMemsetAsync(counts, 0, (size_t)NV * 4, stream);
  hist_k<<<dim3(EE / 256), dim3(256), 0, stream>>>(er, ec, counts);
  scan1<<<dim3(NB2), dim3(256), 0, stream>>>(counts, bsums);
  scan2<<<dim3(1), dim3(1024), 0, stream>>>(bsums, boffs);
  scan3<<<dim3(NB2), dim3(256), 0, stream>>>(counts, boffs, colptr, cursor);
  scatter_k<<<dim3(8 * (EE / 256)), dim3(256), 0, stream>>>(er, ec, ev, cursor, rv);

  // B = gather(Omega_1 @ U) + Omega_2 @ U  (Bb holds bf16 B); X_0 = B
  gemm_k<<<dim3(512), dim3(256), 0, stream>>>(Om1b, Ub, Xwb);
  gemm_k<<<dim3(512), dim3(256), 0, stream>>>(Om2b, Ub, Bb);
  spmm_k<0><<<dim3(NN / 16), dim3(256), 0, stream>>>(colptr, rv, (const u16*)Xwb,
                                                     Bb, (u32*)nullptr, (float*)nullptr);

  // 20 fixed-point iterations (X_0 = B lives in Bb for the first gemm)
  for (int it = 0; it < ITERS; ++it) {
    const u16* xsrc = (it == 0) ? (const u16*)Bb : (const u16*)Xb;
    gemm_k<<<dim3(512), dim3(256), 0, stream>>>(Wb, xsrc, Xwb);
    if (it < ITERS - 1)
      spmm_k<1><<<dim3(NN / 16), dim3(256), 0, stream>>>(colptr, rv, (const u16*)Xwb,
                                                         Bb, Xb, (float*)nullptr);
    else
      spmm_k<2><<<dim3(NN / 16), dim3(256), 0, stream>>>(colptr, rv, (const u16*)Xwb,
                                                         Bb, (u32*)nullptr, Xf);
  }

  transpose_out<<<dim3((NN + 63) / 64), dim3(256), 0, stream>>>(Xf, out, NN);
}